// Round 6
// baseline (519.357 us; speedup 1.0000x reference)
//
#include <hip/hip_runtime.h>
#include <hip/hip_bf16.h>

// ---------------------------------------------------------------------------
// LSTM_net: 6x biLSTM(H=8, T=4) + composed affine head, B=131072. All f32.
// Round 12: lane-per-element layout. Each lane runs the full LSTM cell for
// one batch element: h/c recurrence entirely in registers (no LDS / DPP on
// the serial chain). KEY LAW (r7-r11 post-mortems): weight addresses must be
// wave-uniform -> here every lane uses the SAME weights at the same program
// point, so the compiler emits scalar (SGPR) loads; per-lane VGPR state is
// ~70 regs. Layer activations pass through LDS [t][ch-pair][lane] (adjacent
// lanes -> adjacent addresses, 2-way bank aliasing = free; b64 accesses).
// 64-thread single-wave blocks: no cross-lane deps, __syncthreads ~ free,
// 32 KB LDS -> 5 blocks/CU. Head matrix M stored TRANSPOSED by prep so its
// scalar loads merge into wide s_loads.
// ---------------------------------------------------------------------------

using f32x2 = __attribute__((ext_vector_type(2))) float;
using f32x4 = __attribute__((ext_vector_type(4))) float;

#define OFF_WIH0 0      // [2][32][2]   = 128
#define OFF_WHH0 128    // [2][32][8]   = 512
#define OFF_B0   640    // [2][32]      = 64   (b_ih0 + b_hh0)
#define OFF_WIH  704    // [5][2][32][16] = 5120
#define OFF_WHH  5824   // [5][2][32][8]  = 2560
#define OFF_B    8384   // [5][2][32]     = 640 (b_ih + b_hh)
#define OFF_M    9024   // [64][16]       = 1024 (composed head, TRANSPOSED)
#define OFF_MB   10048  // [16]           = 16   (composed head, bias)

__device__ __forceinline__ float rcpf_(float x) {
#if __has_builtin(__builtin_amdgcn_rcpf)
    return __builtin_amdgcn_rcpf(x);
#else
    return 1.0f / x;
#endif
}
__device__ __forceinline__ float exp2f_(float x) {
#if __has_builtin(__builtin_amdgcn_exp2f)
    return __builtin_amdgcn_exp2f(x);
#else
    return exp2f(x);
#endif
}
__device__ __forceinline__ float sigm(float x) {
    return rcpf_(1.0f + exp2f_(-1.44269504f * x));
}
__device__ __forceinline__ float tanhx(float x) {
    return fmaf(2.0f, rcpf_(1.0f + exp2f_(-2.88539008f * x)), -1.0f);
}

// ---------------------------------------------------------------------------
// prep (fused): blocks 0..35 repack LSTM weights (plain copy, natural order);
// blocks 36..40 compose the affine conv/deconv/fc head into M + Mb.
// M is stored TRANSPOSED: W[OFF_M + col*16 + row] (head consumes col-major).
// (head composition verified rounds 2-5; only the final store layout changed)
// ---------------------------------------------------------------------------
__global__ __launch_bounds__(256) void prep_all(
    const float* __restrict__ wih0, const float* __restrict__ whh0,
    const float* __restrict__ bih0, const float* __restrict__ bhh0,
    const float* __restrict__ wih,  const float* __restrict__ whh,
    const float* __restrict__ bih,  const float* __restrict__ bhh,
    const float* __restrict__ c1w, const float* __restrict__ c1b,
    const float* __restrict__ c2w, const float* __restrict__ c2b,
    const float* __restrict__ d1w, const float* __restrict__ d1b,
    const float* __restrict__ d2w, const float* __restrict__ d2b,
    const float* __restrict__ f1w, const float* __restrict__ f1b,
    const float* __restrict__ f2w, const float* __restrict__ f2b,
    float* __restrict__ W)
{
    __shared__ float A[13][232];
    __shared__ float Bf[13][232];
    const int tid = threadIdx.x;

    if (blockIdx.x < 36) {
        int t = blockIdx.x * 256 + tid;
        const int n = 36 * 256;
        for (int i = t; i < 128; i += n)  W[OFF_WIH0 + i] = wih0[i];
        for (int i = t; i < 512; i += n)  W[OFF_WHH0 + i] = whh0[i];
        for (int i = t; i < 64; i += n)   W[OFF_B0 + i] = bih0[i] + bhh0[i];
        for (int i = t; i < 5120; i += n) W[OFF_WIH + i] = wih[i];
        for (int i = t; i < 2560; i += n) W[OFF_WHH + i] = whh[i];
        for (int i = t; i < 640; i += n)  W[OFF_B + i] = bih[i] + bhh[i];
        return;
    }
    const int base = (blockIdx.x - 36) * 13;

    for (int idx = tid; idx < 13 * 64; idx += 256) {
        int cl = idx / 64, r = idx % 64;
        A[cl][r] = (base + cl == r) ? 1.0f : 0.0f;
    }
    __syncthreads();
    for (int idx = tid; idx < 13 * 120; idx += 256) {
        int cl = idx / 120, rr = idx % 120; int o = rr / 15, l = rr % 15;
        float acc = (base + cl == 64) ? c1b[o] : 0.0f;
        for (int i = 0; i < 4; i++)
            for (int kk = 0; kk < 2; kk++)
                acc += c1w[(o * 4 + i) * 2 + kk] * A[cl][i * 16 + l + kk];
        Bf[cl][rr] = acc;
    }
    __syncthreads();
    for (int idx = tid; idx < 13 * 224; idx += 256) {
        int cl = idx / 224, rr = idx % 224; int o = rr / 14, l = rr % 14;
        float acc = (base + cl == 64) ? c2b[o] : 0.0f;
        for (int i = 0; i < 8; i++)
            for (int kk = 0; kk < 2; kk++)
                acc += c2w[(o * 8 + i) * 2 + kk] * Bf[cl][i * 15 + l + kk];
        A[cl][rr] = acc;
    }
    __syncthreads();
    for (int idx = tid; idx < 13 * 120; idx += 256) {
        int cl = idx / 120, rr = idx % 120; int o = rr / 15, l = rr % 15;
        float acc = (base + cl == 64) ? d1b[o] : 0.0f;
        for (int i = 0; i < 16; i++)
            for (int kk = 0; kk < 2; kk++) {
                int ls = l - kk;
                if (ls >= 0 && ls < 14)
                    acc += d1w[(i * 8 + o) * 2 + kk] * A[cl][i * 14 + ls];
            }
        Bf[cl][rr] = acc;
    }
    __syncthreads();
    for (int idx = tid; idx < 13 * 64; idx += 256) {
        int cl = idx / 64, rr = idx % 64; int o = rr / 16, l = rr % 16;
        float acc = (base + cl == 64) ? d2b[o] : 0.0f;
        for (int i = 0; i < 8; i++)
            for (int kk = 0; kk < 2; kk++) {
                int ls = l - kk;
                if (ls >= 0 && ls < 15)
                    acc += d2w[(i * 4 + o) * 2 + kk] * Bf[cl][i * 15 + ls];
            }
        A[cl][rr] = acc;
    }
    __syncthreads();
    for (int idx = tid; idx < 13 * 32; idx += 256) {
        int cl = idx / 32, rr = idx % 32; int ch = rr / 8, jj = rr % 8;
        float acc = (base + cl == 64) ? f1b[jj] : 0.0f;
        for (int l = 0; l < 16; l++)
            acc += f1w[jj * 16 + l] * A[cl][ch * 16 + l];
        Bf[cl][rr] = acc;
    }
    __syncthreads();
    for (int idx = tid; idx < 13 * 16; idx += 256) {
        int cl = idx / 16, rr = idx % 16; int ch = rr / 4, m = rr % 4;
        int col = base + cl;
        if (col > 64) continue;
        float acc = (col == 64) ? f2b[m] : 0.0f;
        for (int j = 0; j < 8; j++)
            acc += f2w[m * 8 + j] * Bf[cl][ch * 8 + j];
        if (col < 64) W[OFF_M + col * 16 + rr] = acc;   // TRANSPOSED store
        else          W[OFF_MB + rr] = acc;
    }
}

// ---------------------------------------------------------------------------
// main: block = 64 threads = 1 wave; lane owns one element end-to-end.
// LDS: activation ping-pong yb[buf][t][ch-pair][lane] (f32x2), 32 KB.
// ---------------------------------------------------------------------------
__global__ __launch_bounds__(64) void lstm_main(
    const float* __restrict__ x, const float* __restrict__ h0,
    const float* __restrict__ c0, const float* __restrict__ W,
    float* __restrict__ out, int B)
{
    __shared__ f32x2 yb[2][4][8][64];
    const int lane = threadIdx.x;
    const int gelem = blockIdx.x * 64 + lane;
    const size_t B8 = (size_t)B * 8;

    // ---------------- layer 0 (Din=2), x in registers ----------------
    float xs[8];
    {
        const f32x4* xp4 = reinterpret_cast<const f32x4*>(x + (size_t)gelem * 8);
        f32x4 a = xp4[0], b = xp4[1];
        xs[0] = a.x; xs[1] = a.y; xs[2] = a.z; xs[3] = a.w;
        xs[4] = b.x; xs[5] = b.y; xs[6] = b.z; xs[7] = b.w;
    }
    for (int d = 0; d < 2; ++d) {
        const float* wi = W + OFF_WIH0 + d * 64;    // rows of 2
        const float* wh = W + OFF_WHH0 + d * 256;   // rows of 8
        const float* bb = W + OFF_B0 + d * 32;
        const float* hp = h0 + (size_t)d * B8 + (size_t)gelem * 8;
        const float* cp = c0 + (size_t)d * B8 + (size_t)gelem * 8;
        f32x4 ha = reinterpret_cast<const f32x4*>(hp)[0];
        f32x4 hb = reinterpret_cast<const f32x4*>(hp)[1];
        f32x4 ca = reinterpret_cast<const f32x4*>(cp)[0];
        f32x4 cb = reinterpret_cast<const f32x4*>(cp)[1];
        f32x2 hx2[4] = { f32x2{ha.x,ha.y}, f32x2{ha.z,ha.w},
                         f32x2{hb.x,hb.y}, f32x2{hb.z,hb.w} };
        float c[8] = { ca.x,ca.y,ca.z,ca.w, cb.x,cb.y,cb.z,cb.w };
#pragma unroll
        for (int s = 0; s < 4; ++s) {
            const int t = d ? (3 - s) : s;
            // static-index select of x[t] (both arms compile-time)
            f32x2 xin = d ? f32x2{xs[2 * (3 - s)], xs[2 * (3 - s) + 1]}
                          : f32x2{xs[2 * s],       xs[2 * s + 1]};
            float hnew[8];
#pragma unroll
            for (int u = 0; u < 8; ++u) {
                f32x2 a4[4];
#pragma unroll
                for (int g = 0; g < 4; ++g) {
                    const int r = 8 * g + u;
                    f32x2 aa = f32x2{bb[r], 0.0f};
                    aa = __builtin_elementwise_fma(xin,
                            *reinterpret_cast<const f32x2*>(wi + r * 2), aa);
                    const f32x2* wh2 = reinterpret_cast<const f32x2*>(wh + r * 8);
#pragma unroll
                    for (int j = 0; j < 4; ++j)
                        aa = __builtin_elementwise_fma(hx2[j], wh2[j], aa);
                    a4[g] = aa;
                }
                float ii = sigm(a4[0].x + a4[0].y);
                float ff = sigm(a4[1].x + a4[1].y);
                float gg = tanhx(a4[2].x + a4[2].y);
                float oo = sigm(a4[3].x + a4[3].y);
                c[u] = fmaf(ff, c[u], ii * gg);
                hnew[u] = oo * tanhx(c[u]);
            }
#pragma unroll
            for (int k = 0; k < 4; ++k)
                yb[0][t][d * 4 + k][lane] = f32x2{hnew[2 * k], hnew[2 * k + 1]};
            hx2[0] = f32x2{hnew[0], hnew[1]}; hx2[1] = f32x2{hnew[2], hnew[3]};
            hx2[2] = f32x2{hnew[4], hnew[5]}; hx2[3] = f32x2{hnew[6], hnew[7]};
        }
    }
    __syncthreads();

    // ---------------- layers 1..5 (Din=16) ----------------
    for (int l = 1; l <= 5; ++l) {
        const int inb = (l & 1) ? 0 : 1;
        const int oub = 1 - inb;
        const bool last = (l == 5);
        for (int d = 0; d < 2; ++d) {
            const float* wi = W + OFF_WIH + (size_t)(l - 1) * 1024 + d * 512; // rows of 16
            const float* wh = W + OFF_WHH + (size_t)(l - 1) * 512 + d * 256;  // rows of 8
            const float* bb = W + OFF_B + (size_t)(l - 1) * 64 + d * 32;
            const int si = 2 * l + d;
            const float* hp = h0 + (size_t)si * B8 + (size_t)gelem * 8;
            const float* cp = c0 + (size_t)si * B8 + (size_t)gelem * 8;
            f32x4 ha = reinterpret_cast<const f32x4*>(hp)[0];
            f32x4 hb = reinterpret_cast<const f32x4*>(hp)[1];
            f32x4 ca = reinterpret_cast<const f32x4*>(cp)[0];
            f32x4 cb = reinterpret_cast<const f32x4*>(cp)[1];
            f32x2 hx2[4] = { f32x2{ha.x,ha.y}, f32x2{ha.z,ha.w},
                             f32x2{hb.x,hb.y}, f32x2{hb.z,hb.w} };
            float c[8] = { ca.x,ca.y,ca.z,ca.w, cb.x,cb.y,cb.z,cb.w };
#pragma unroll
            for (int s = 0; s < 4; ++s) {
                const int t = d ? (3 - s) : s;
                f32x2 xp[8];
#pragma unroll
                for (int k = 0; k < 8; ++k)
                    xp[k] = yb[inb][t][k][lane];
                float hnew[8];
#pragma unroll
                for (int u = 0; u < 8; ++u) {
                    f32x2 a4[4];
#pragma unroll
                    for (int g = 0; g < 4; ++g) {
                        const int r = 8 * g + u;
                        const f32x2* wi2 = reinterpret_cast<const f32x2*>(wi + r * 16);
                        const f32x2* wh2 = reinterpret_cast<const f32x2*>(wh + r * 8);
                        f32x2 aa = f32x2{bb[r], 0.0f};
#pragma unroll
                        for (int j = 0; j < 8; ++j)
                            aa = __builtin_elementwise_fma(xp[j], wi2[j], aa);
#pragma unroll
                        for (int j = 0; j < 4; ++j)
                            aa = __builtin_elementwise_fma(hx2[j], wh2[j], aa);
                        a4[g] = aa;
                    }
                    float ii = sigm(a4[0].x + a4[0].y);
                    float ff = sigm(a4[1].x + a4[1].y);
                    float gg = tanhx(a4[2].x + a4[2].y);
                    float oo = sigm(a4[3].x + a4[3].y);
                    c[u] = fmaf(ff, c[u], ii * gg);
                    hnew[u] = oo * tanhx(c[u]);
                }
                if (last) {
#pragma unroll
                    for (int k = 0; k < 4; ++k)
                        yb[oub][t][d * 4 + k][lane] =
                            f32x2{sigm(hnew[2 * k]), sigm(hnew[2 * k + 1])};
                } else {
#pragma unroll
                    for (int k = 0; k < 4; ++k)
                        yb[oub][t][d * 4 + k][lane] =
                            f32x2{hnew[2 * k], hnew[2 * k + 1]};
                }
                hx2[0] = f32x2{hnew[0], hnew[1]}; hx2[1] = f32x2{hnew[2], hnew[3]};
                hx2[2] = f32x2{hnew[4], hnew[5]}; hx2[3] = f32x2{hnew[6], hnew[7]};
            }
        }
        __syncthreads();
    }

    // ---------------- head: out = tanh(M_T^T @ s + Mb), s = yb[1] ----------
    float acc[16];
#pragma unroll
    for (int o = 0; o < 16; ++o) acc[o] = W[OFF_MB + o];
#pragma unroll
    for (int t2 = 0; t2 < 4; ++t2) {
#pragma unroll
        for (int p = 0; p < 8; ++p) {
            f32x2 sv = yb[1][t2][p][lane];
            const int cA = (t2 * 16 + 2 * p) * 16;   // M transposed: [col][16]
            const int cB = cA + 16;
#pragma unroll
            for (int o = 0; o < 16; ++o) {
                acc[o] = fmaf(sv.x, W[OFF_M + cA + o], acc[o]);
                acc[o] = fmaf(sv.y, W[OFF_M + cB + o], acc[o]);
            }
        }
    }
    f32x4* op = reinterpret_cast<f32x4*>(out + (size_t)gelem * 16);
#pragma unroll
    for (int q = 0; q < 4; ++q) {
        f32x4 r;
        r.x = tanhx(acc[4 * q + 0]);
        r.y = tanhx(acc[4 * q + 1]);
        r.z = tanhx(acc[4 * q + 2]);
        r.w = tanhx(acc[4 * q + 3]);
        op[q] = r;
    }
}

extern "C" void kernel_launch(void* const* d_in, const int* in_sizes, int n_in,
                              void* d_out, int out_size, void* d_ws, size_t ws_size,
                              hipStream_t stream)
{
    const float* x    = (const float*)d_in[0];
    const float* h0   = (const float*)d_in[1];
    const float* c0   = (const float*)d_in[2];
    const float* wih0 = (const float*)d_in[3];
    const float* whh0 = (const float*)d_in[4];
    const float* bih0 = (const float*)d_in[5];
    const float* bhh0 = (const float*)d_in[6];
    const float* wih  = (const float*)d_in[7];
    const float* whh  = (const float*)d_in[8];
    const float* bih  = (const float*)d_in[9];
    const float* bhh  = (const float*)d_in[10];
    const float* c1w  = (const float*)d_in[11];
    const float* c1b  = (const float*)d_in[12];
    const float* c2w  = (const float*)d_in[13];
    const float* c2b  = (const float*)d_in[14];
    const float* d1w  = (const float*)d_in[15];
    const float* d1b  = (const float*)d_in[16];
    const float* d2w  = (const float*)d_in[17];
    const float* d2b  = (const float*)d_in[18];
    const float* f1w  = (const float*)d_in[19];
    const float* f1b  = (const float*)d_in[20];
    const float* f2w  = (const float*)d_in[21];
    const float* f2b  = (const float*)d_in[22];

    float* W = (float*)d_ws;
    const int B = in_sizes[0] / 8;

    prep_all<<<41, 256, 0, stream>>>(wih0, whh0, bih0, bhh0, wih, whh, bih, bhh,
                                     c1w, c1b, c2w, c2b, d1w, d1b, d2w, d2b,
                                     f1w, f1b, f2w, f2b, W);
    lstm_main<<<B / 64, 64, 0, stream>>>(x, h0, c0, W, (float*)d_out, B);
}

// Round 7
// 517.060 us; speedup vs baseline: 1.0044x; 1.0044x over previous
//
#include <hip/hip_runtime.h>
#include <hip/hip_bf16.h>

// ---------------------------------------------------------------------------
// LSTM_net: 6x biLSTM(H=8, T=4) + composed affine head, B=131072. All f32.
// Round 13: r12 lane-per-element design (no-spill verified: FETCH 52MB,
// WRITE 8MB) with the LDS activation ping-pong moved into REGISTERS.
// There is no cross-lane dataflow in this layout -> LDS was pure pressure
// relief, but it capped residency at 5 waves/CU (32KB/1-wave block) while
// the grid offers 8. Register ping-pong (f32x2[4][8] x2, all indices
// compile-time, d/s/u fully unrolled) removes the LDS cap and ~12 LDS
// instructions + lgkmcnt waits per layer-step. Weights stay wave-uniform
// (SGPR-addressed s_loads) per the r7-r11 law.
// ---------------------------------------------------------------------------

using f32x2 = __attribute__((ext_vector_type(2))) float;
using f32x4 = __attribute__((ext_vector_type(4))) float;

#define OFF_WIH0 0      // [2][32][2]   = 128
#define OFF_WHH0 128    // [2][32][8]   = 512
#define OFF_B0   640    // [2][32]      = 64   (b_ih0 + b_hh0)
#define OFF_WIH  704    // [5][2][32][16] = 5120
#define OFF_WHH  5824   // [5][2][32][8]  = 2560
#define OFF_B    8384   // [5][2][32]     = 640 (b_ih + b_hh)
#define OFF_M    9024   // [64][16]       = 1024 (composed head, TRANSPOSED)
#define OFF_MB   10048  // [16]           = 16   (composed head, bias)

__device__ __forceinline__ float rcpf_(float x) {
#if __has_builtin(__builtin_amdgcn_rcpf)
    return __builtin_amdgcn_rcpf(x);
#else
    return 1.0f / x;
#endif
}
__device__ __forceinline__ float exp2f_(float x) {
#if __has_builtin(__builtin_amdgcn_exp2f)
    return __builtin_amdgcn_exp2f(x);
#else
    return exp2f(x);
#endif
}
__device__ __forceinline__ float sigm(float x) {
    return rcpf_(1.0f + exp2f_(-1.44269504f * x));
}
__device__ __forceinline__ float tanhx(float x) {
    return fmaf(2.0f, rcpf_(1.0f + exp2f_(-2.88539008f * x)), -1.0f);
}

// ---------------------------------------------------------------------------
// prep (fused): blocks 0..35 repack LSTM weights (plain copy, natural order);
// blocks 36..40 compose the affine conv/deconv/fc head into M + Mb.
// M is stored TRANSPOSED: W[OFF_M + col*16 + row].  (verified r2-r6)
// ---------------------------------------------------------------------------
__global__ __launch_bounds__(256) void prep_all(
    const float* __restrict__ wih0, const float* __restrict__ whh0,
    const float* __restrict__ bih0, const float* __restrict__ bhh0,
    const float* __restrict__ wih,  const float* __restrict__ whh,
    const float* __restrict__ bih,  const float* __restrict__ bhh,
    const float* __restrict__ c1w, const float* __restrict__ c1b,
    const float* __restrict__ c2w, const float* __restrict__ c2b,
    const float* __restrict__ d1w, const float* __restrict__ d1b,
    const float* __restrict__ d2w, const float* __restrict__ d2b,
    const float* __restrict__ f1w, const float* __restrict__ f1b,
    const float* __restrict__ f2w, const float* __restrict__ f2b,
    float* __restrict__ W)
{
    __shared__ float A[13][232];
    __shared__ float Bf[13][232];
    const int tid = threadIdx.x;

    if (blockIdx.x < 36) {
        int t = blockIdx.x * 256 + tid;
        const int n = 36 * 256;
        for (int i = t; i < 128; i += n)  W[OFF_WIH0 + i] = wih0[i];
        for (int i = t; i < 512; i += n)  W[OFF_WHH0 + i] = whh0[i];
        for (int i = t; i < 64; i += n)   W[OFF_B0 + i] = bih0[i] + bhh0[i];
        for (int i = t; i < 5120; i += n) W[OFF_WIH + i] = wih[i];
        for (int i = t; i < 2560; i += n) W[OFF_WHH + i] = whh[i];
        for (int i = t; i < 640; i += n)  W[OFF_B + i] = bih[i] + bhh[i];
        return;
    }
    const int base = (blockIdx.x - 36) * 13;

    for (int idx = tid; idx < 13 * 64; idx += 256) {
        int cl = idx / 64, r = idx % 64;
        A[cl][r] = (base + cl == r) ? 1.0f : 0.0f;
    }
    __syncthreads();
    for (int idx = tid; idx < 13 * 120; idx += 256) {
        int cl = idx / 120, rr = idx % 120; int o = rr / 15, l = rr % 15;
        float acc = (base + cl == 64) ? c1b[o] : 0.0f;
        for (int i = 0; i < 4; i++)
            for (int kk = 0; kk < 2; kk++)
                acc += c1w[(o * 4 + i) * 2 + kk] * A[cl][i * 16 + l + kk];
        Bf[cl][rr] = acc;
    }
    __syncthreads();
    for (int idx = tid; idx < 13 * 224; idx += 256) {
        int cl = idx / 224, rr = idx % 224; int o = rr / 14, l = rr % 14;
        float acc = (base + cl == 64) ? c2b[o] : 0.0f;
        for (int i = 0; i < 8; i++)
            for (int kk = 0; kk < 2; kk++)
                acc += c2w[(o * 8 + i) * 2 + kk] * Bf[cl][i * 15 + l + kk];
        A[cl][rr] = acc;
    }
    __syncthreads();
    for (int idx = tid; idx < 13 * 120; idx += 256) {
        int cl = idx / 120, rr = idx % 120; int o = rr / 15, l = rr % 15;
        float acc = (base + cl == 64) ? d1b[o] : 0.0f;
        for (int i = 0; i < 16; i++)
            for (int kk = 0; kk < 2; kk++) {
                int ls = l - kk;
                if (ls >= 0 && ls < 14)
                    acc += d1w[(i * 8 + o) * 2 + kk] * A[cl][i * 14 + ls];
            }
        Bf[cl][rr] = acc;
    }
    __syncthreads();
    for (int idx = tid; idx < 13 * 64; idx += 256) {
        int cl = idx / 64, rr = idx % 64; int o = rr / 16, l = rr % 16;
        float acc = (base + cl == 64) ? d2b[o] : 0.0f;
        for (int i = 0; i < 8; i++)
            for (int kk = 0; kk < 2; kk++) {
                int ls = l - kk;
                if (ls >= 0 && ls < 15)
                    acc += d2w[(i * 4 + o) * 2 + kk] * Bf[cl][i * 15 + ls];
            }
        A[cl][rr] = acc;
    }
    __syncthreads();
    for (int idx = tid; idx < 13 * 32; idx += 256) {
        int cl = idx / 32, rr = idx % 32; int ch = rr / 8, jj = rr % 8;
        float acc = (base + cl == 64) ? f1b[jj] : 0.0f;
        for (int l = 0; l < 16; l++)
            acc += f1w[jj * 16 + l] * A[cl][ch * 16 + l];
        Bf[cl][rr] = acc;
    }
    __syncthreads();
    for (int idx = tid; idx < 13 * 16; idx += 256) {
        int cl = idx / 16, rr = idx % 16; int ch = rr / 4, m = rr % 4;
        int col = base + cl;
        if (col > 64) continue;
        float acc = (col == 64) ? f2b[m] : 0.0f;
        for (int j = 0; j < 8; j++)
            acc += f2w[m * 8 + j] * Bf[cl][ch * 8 + j];
        if (col < 64) W[OFF_M + col * 16 + rr] = acc;   // TRANSPOSED store
        else          W[OFF_MB + rr] = acc;
    }
}

// ---------------------------------------------------------------------------
// main: block = 64 threads = 1 wave; lane owns one element end-to-end.
// Activations ping-pong entirely in registers (f32x2[4][8] x 2).  No LDS.
// ---------------------------------------------------------------------------
__global__ __launch_bounds__(64) void lstm_main(
    const float* __restrict__ x, const float* __restrict__ h0,
    const float* __restrict__ c0, const float* __restrict__ W,
    float* __restrict__ out, int B)
{
    const int lane = threadIdx.x;
    const int gelem = blockIdx.x * 64 + lane;
    const size_t B8 = (size_t)B * 8;

    f32x2 yin2[4][8];    // register ping buffer: [t][ch-pair]
    f32x2 yout2[4][8];   // register pong buffer

    // ---------------- layer 0 (Din=2), x in registers ----------------
    f32x2 xs2[4];
    {
        const f32x4* xp4 = reinterpret_cast<const f32x4*>(x + (size_t)gelem * 8);
        f32x4 a = xp4[0], b = xp4[1];
        xs2[0] = f32x2{a.x, a.y}; xs2[1] = f32x2{a.z, a.w};
        xs2[2] = f32x2{b.x, b.y}; xs2[3] = f32x2{b.z, b.w};
    }
#pragma unroll
    for (int d = 0; d < 2; ++d) {
        const float* wi = W + OFF_WIH0 + d * 64;    // rows of 2
        const float* wh = W + OFF_WHH0 + d * 256;   // rows of 8
        const float* bb = W + OFF_B0 + d * 32;
        const float* hp = h0 + (size_t)d * B8 + (size_t)gelem * 8;
        const float* cp = c0 + (size_t)d * B8 + (size_t)gelem * 8;
        f32x4 ha = reinterpret_cast<const f32x4*>(hp)[0];
        f32x4 hb = reinterpret_cast<const f32x4*>(hp)[1];
        f32x4 ca = reinterpret_cast<const f32x4*>(cp)[0];
        f32x4 cb = reinterpret_cast<const f32x4*>(cp)[1];
        f32x2 hx2[4] = { f32x2{ha.x,ha.y}, f32x2{ha.z,ha.w},
                         f32x2{hb.x,hb.y}, f32x2{hb.z,hb.w} };
        float c[8] = { ca.x,ca.y,ca.z,ca.w, cb.x,cb.y,cb.z,cb.w };
#pragma unroll
        for (int s = 0; s < 4; ++s) {
            const int t = d ? (3 - s) : s;
            f32x2 xin = d ? xs2[3 - s] : xs2[s];    // compile-time select
            float hnew[8];
#pragma unroll
            for (int u = 0; u < 8; ++u) {
                f32x2 a4[4];
#pragma unroll
                for (int g = 0; g < 4; ++g) {
                    const int r = 8 * g + u;
                    f32x2 aa = f32x2{bb[r], 0.0f};
                    aa = __builtin_elementwise_fma(xin,
                            *reinterpret_cast<const f32x2*>(wi + r * 2), aa);
                    const f32x2* wh2 = reinterpret_cast<const f32x2*>(wh + r * 8);
#pragma unroll
                    for (int j = 0; j < 4; ++j)
                        aa = __builtin_elementwise_fma(hx2[j], wh2[j], aa);
                    a4[g] = aa;
                }
                float ii = sigm(a4[0].x + a4[0].y);
                float ff = sigm(a4[1].x + a4[1].y);
                float gg = tanhx(a4[2].x + a4[2].y);
                float oo = sigm(a4[3].x + a4[3].y);
                c[u] = fmaf(ff, c[u], ii * gg);
                hnew[u] = oo * tanhx(c[u]);
            }
#pragma unroll
            for (int k = 0; k < 4; ++k)
                yin2[t][d * 4 + k] = f32x2{hnew[2 * k], hnew[2 * k + 1]};
            hx2[0] = f32x2{hnew[0], hnew[1]}; hx2[1] = f32x2{hnew[2], hnew[3]};
            hx2[2] = f32x2{hnew[4], hnew[5]}; hx2[3] = f32x2{hnew[6], hnew[7]};
        }
    }

    // ---------------- layers 1..5 (Din=16), register ping-pong -------------
    for (int l = 1; l <= 5; ++l) {
        const float* wiL = W + OFF_WIH + (size_t)(l - 1) * 1024;  // rows of 16
        const float* whL = W + OFF_WHH + (size_t)(l - 1) * 512;   // rows of 8
        const float* bbL = W + OFF_B + (size_t)(l - 1) * 64;
#pragma unroll
        for (int d = 0; d < 2; ++d) {
            const float* wi = wiL + d * 512;
            const float* wh = whL + d * 256;
            const float* bb = bbL + d * 32;
            const int si = 2 * l + d;
            const float* hp = h0 + (size_t)si * B8 + (size_t)gelem * 8;
            const float* cp = c0 + (size_t)si * B8 + (size_t)gelem * 8;
            f32x4 ha = reinterpret_cast<const f32x4*>(hp)[0];
            f32x4 hb = reinterpret_cast<const f32x4*>(hp)[1];
            f32x4 ca = reinterpret_cast<const f32x4*>(cp)[0];
            f32x4 cb = reinterpret_cast<const f32x4*>(cp)[1];
            f32x2 hx2[4] = { f32x2{ha.x,ha.y}, f32x2{ha.z,ha.w},
                             f32x2{hb.x,hb.y}, f32x2{hb.z,hb.w} };
            float c[8] = { ca.x,ca.y,ca.z,ca.w, cb.x,cb.y,cb.z,cb.w };
#pragma unroll
            for (int s = 0; s < 4; ++s) {
                const int t = d ? (3 - s) : s;
                float hnew[8];
#pragma unroll
                for (int u = 0; u < 8; ++u) {
                    f32x2 a4[4];
#pragma unroll
                    for (int g = 0; g < 4; ++g) {
                        const int r = 8 * g + u;
                        const f32x2* wi2 = reinterpret_cast<const f32x2*>(wi + r * 16);
                        const f32x2* wh2 = reinterpret_cast<const f32x2*>(wh + r * 8);
                        f32x2 aa = f32x2{bb[r], 0.0f};
#pragma unroll
                        for (int j = 0; j < 8; ++j)
                            aa = __builtin_elementwise_fma(yin2[t][j], wi2[j], aa);
#pragma unroll
                        for (int j = 0; j < 4; ++j)
                            aa = __builtin_elementwise_fma(hx2[j], wh2[j], aa);
                        a4[g] = aa;
                    }
                    float ii = sigm(a4[0].x + a4[0].y);
                    float ff = sigm(a4[1].x + a4[1].y);
                    float gg = tanhx(a4[2].x + a4[2].y);
                    float oo = sigm(a4[3].x + a4[3].y);
                    c[u] = fmaf(ff, c[u], ii * gg);
                    hnew[u] = oo * tanhx(c[u]);
                }
#pragma unroll
                for (int k = 0; k < 4; ++k)
                    yout2[t][d * 4 + k] = f32x2{hnew[2 * k], hnew[2 * k + 1]};
                hx2[0] = f32x2{hnew[0], hnew[1]}; hx2[1] = f32x2{hnew[2], hnew[3]};
                hx2[2] = f32x2{hnew[4], hnew[5]}; hx2[3] = f32x2{hnew[6], hnew[7]};
            }
        }
        if (l == 5) {
            // final layer feeds the head through sigmoid
#pragma unroll
            for (int t = 0; t < 4; ++t)
#pragma unroll
                for (int p = 0; p < 8; ++p)
                    yout2[t][p] = f32x2{sigm(yout2[t][p].x), sigm(yout2[t][p].y)};
        } else {
            // ping-pong: next layer's input <- this layer's output
#pragma unroll
            for (int t = 0; t < 4; ++t)
#pragma unroll
                for (int p = 0; p < 8; ++p)
                    yin2[t][p] = yout2[t][p];
        }
    }

    // ---------------- head: out = tanh(M_T^T @ s + Mb), s = yout2 ----------
    float acc[16];
#pragma unroll
    for (int o = 0; o < 16; ++o) acc[o] = W[OFF_MB + o];
#pragma unroll
    for (int t2 = 0; t2 < 4; ++t2) {
#pragma unroll
        for (int p = 0; p < 8; ++p) {
            f32x2 sv = yout2[t2][p];
            const int cA = (t2 * 16 + 2 * p) * 16;   // M transposed: [col][16]
            const int cB = cA + 16;
#pragma unroll
            for (int o = 0; o < 16; ++o) {
                acc[o] = fmaf(sv.x, W[OFF_M + cA + o], acc[o]);
                acc[o] = fmaf(sv.y, W[OFF_M + cB + o], acc[o]);
            }
        }
    }
    f32x4* op = reinterpret_cast<f32x4*>(out + (size_t)gelem * 16);
#pragma unroll
    for (int q = 0; q < 4; ++q) {
        f32x4 r;
        r.x = tanhx(acc[4 * q + 0]);
        r.y = tanhx(acc[4 * q + 1]);
        r.z = tanhx(acc[4 * q + 2]);
        r.w = tanhx(acc[4 * q + 3]);
        op[q] = r;
    }
}

extern "C" void kernel_launch(void* const* d_in, const int* in_sizes, int n_in,
                              void* d_out, int out_size, void* d_ws, size_t ws_size,
                              hipStream_t stream)
{
    const float* x    = (const float*)d_in[0];
    const float* h0   = (const float*)d_in[1];
    const float* c0   = (const float*)d_in[2];
    const float* wih0 = (const float*)d_in[3];
    const float* whh0 = (const float*)d_in[4];
    const float* bih0 = (const float*)d_in[5];
    const float* bhh0 = (const float*)d_in[6];
    const float* wih  = (const float*)d_in[7];
    const float* whh  = (const float*)d_in[8];
    const float* bih  = (const float*)d_in[9];
    const float* bhh  = (const float*)d_in[10];
    const float* c1w  = (const float*)d_in[11];
    const float* c1b  = (const float*)d_in[12];
    const float* c2w  = (const float*)d_in[13];
    const float* c2b  = (const float*)d_in[14];
    const float* d1w  = (const float*)d_in[15];
    const float* d1b  = (const float*)d_in[16];
    const float* d2w  = (const float*)d_in[17];
    const float* d2b  = (const float*)d_in[18];
    const float* f1w  = (const float*)d_in[19];
    const float* f1b  = (const float*)d_in[20];
    const float* f2w  = (const float*)d_in[21];
    const float* f2b  = (const float*)d_in[22];

    float* W = (float*)d_ws;
    const int B = in_sizes[0] / 8;

    prep_all<<<41, 256, 0, stream>>>(wih0, whh0, bih0, bhh0, wih, whh, bih, bhh,
                                     c1w, c1b, c2w, c2b, d1w, d1b, d2w, d2b,
                                     f1w, f1b, f2w, f2b, W);
    lstm_main<<<B / 64, 64, 0, stream>>>(x, h0, c0, W, (float*)d_out, B);
}

// Round 8
// 388.266 us; speedup vs baseline: 1.3376x; 1.3317x over previous
//
#include <hip/hip_runtime.h>
#include <hip/hip_bf16.h>

// ---------------------------------------------------------------------------
// LSTM_net: 6x biLSTM(H=8, T=4) + composed affine head, B=131072. All f32.
// Round 14: r0 skeleton (per-lane weight rows in VGPRs -> packed v_pk_fma,
// h via same-wave LDS store+readback, E=2 — the only verified no-spill
// shape), with the fwd/bwd directions split ACROSS WAVES: in each 128-thread
// block, wave 0 runs fwd and wave 1 runs bwd for the same 16 elements,
// writing disjoint column halves. dir is pinned to an SGPR via
// readfirstlane so all weight addresses stay wave-uniform (r5's lane-split
// failed exactly because dir was lane-divergent). Serial chain halves
// (24 steps vs 48); LDS/block drops to 8.7 KB -> occupancy VGPR-limited
// (~6 waves/SIMD) instead of LDS-limited (r0: 4).
// ---------------------------------------------------------------------------

using f32x2 = __attribute__((ext_vector_type(2))) float;
using f32x4 = __attribute__((ext_vector_type(4))) float;

#define OFF_WIH0 0      // [2][32][2]   = 128
#define OFF_WHH0 128    // [2][32][8]   = 512
#define OFF_B0   640    // [2][32]      = 64   (b_ih0 + b_hh0)
#define OFF_WIH  704    // [5][2][32][16] = 5120
#define OFF_WHH  5824   // [5][2][32][8]  = 2560
#define OFF_B    8384   // [5][2][32]     = 640 (b_ih + b_hh)
#define OFF_M    9024   // [16][64]       = 1024 (composed conv head, linear)
#define OFF_MB   10048  // [16]           = 16   (composed conv head, bias)

__device__ __forceinline__ float rcpf_(float x) {
#if __has_builtin(__builtin_amdgcn_rcpf)
    return __builtin_amdgcn_rcpf(x);
#else
    return 1.0f / x;
#endif
}
__device__ __forceinline__ float exp2f_(float x) {
#if __has_builtin(__builtin_amdgcn_exp2f)
    return __builtin_amdgcn_exp2f(x);
#else
    return exp2f(x);
#endif
}
__device__ __forceinline__ float sigm(float x) {
    return rcpf_(1.0f + exp2f_(-1.44269504f * x));
}
__device__ __forceinline__ float tanhx(float x) {
    return fmaf(2.0f, rcpf_(1.0f + exp2f_(-2.88539008f * x)), -1.0f);
}

// ---------------------------------------------------------------------------
// prep (fused): blocks 0..35 repack LSTM weights (plain copy, natural order);
// blocks 36..40 compose the affine conv/deconv/fc head into M[16x64]+Mb[16]
// (row-major M, as consumed by the per-lane head).  (verified rounds 2-5)
// ---------------------------------------------------------------------------
__global__ __launch_bounds__(256) void prep_all(
    const float* __restrict__ wih0, const float* __restrict__ whh0,
    const float* __restrict__ bih0, const float* __restrict__ bhh0,
    const float* __restrict__ wih,  const float* __restrict__ whh,
    const float* __restrict__ bih,  const float* __restrict__ bhh,
    const float* __restrict__ c1w, const float* __restrict__ c1b,
    const float* __restrict__ c2w, const float* __restrict__ c2b,
    const float* __restrict__ d1w, const float* __restrict__ d1b,
    const float* __restrict__ d2w, const float* __restrict__ d2b,
    const float* __restrict__ f1w, const float* __restrict__ f1b,
    const float* __restrict__ f2w, const float* __restrict__ f2b,
    float* __restrict__ W)
{
    __shared__ float A[13][232];
    __shared__ float Bf[13][232];
    const int tid = threadIdx.x;

    if (blockIdx.x < 36) {
        int t = blockIdx.x * 256 + tid;
        const int n = 36 * 256;
        for (int i = t; i < 128; i += n)  W[OFF_WIH0 + i] = wih0[i];
        for (int i = t; i < 512; i += n)  W[OFF_WHH0 + i] = whh0[i];
        for (int i = t; i < 64; i += n)   W[OFF_B0 + i] = bih0[i] + bhh0[i];
        for (int i = t; i < 5120; i += n) W[OFF_WIH + i] = wih[i];
        for (int i = t; i < 2560; i += n) W[OFF_WHH + i] = whh[i];
        for (int i = t; i < 640; i += n)  W[OFF_B + i] = bih[i] + bhh[i];
        return;
    }
    const int base = (blockIdx.x - 36) * 13;

    for (int idx = tid; idx < 13 * 64; idx += 256) {
        int cl = idx / 64, r = idx % 64;
        A[cl][r] = (base + cl == r) ? 1.0f : 0.0f;
    }
    __syncthreads();
    for (int idx = tid; idx < 13 * 120; idx += 256) {
        int cl = idx / 120, rr = idx % 120; int o = rr / 15, l = rr % 15;
        float acc = (base + cl == 64) ? c1b[o] : 0.0f;
        for (int i = 0; i < 4; i++)
            for (int kk = 0; kk < 2; kk++)
                acc += c1w[(o * 4 + i) * 2 + kk] * A[cl][i * 16 + l + kk];
        Bf[cl][rr] = acc;
    }
    __syncthreads();
    for (int idx = tid; idx < 13 * 224; idx += 256) {
        int cl = idx / 224, rr = idx % 224; int o = rr / 14, l = rr % 14;
        float acc = (base + cl == 64) ? c2b[o] : 0.0f;
        for (int i = 0; i < 8; i++)
            for (int kk = 0; kk < 2; kk++)
                acc += c2w[(o * 8 + i) * 2 + kk] * Bf[cl][i * 15 + l + kk];
        A[cl][rr] = acc;
    }
    __syncthreads();
    for (int idx = tid; idx < 13 * 120; idx += 256) {
        int cl = idx / 120, rr = idx % 120; int o = rr / 15, l = rr % 15;
        float acc = (base + cl == 64) ? d1b[o] : 0.0f;
        for (int i = 0; i < 16; i++)
            for (int kk = 0; kk < 2; kk++) {
                int ls = l - kk;
                if (ls >= 0 && ls < 14)
                    acc += d1w[(i * 8 + o) * 2 + kk] * A[cl][i * 14 + ls];
            }
        Bf[cl][rr] = acc;
    }
    __syncthreads();
    for (int idx = tid; idx < 13 * 64; idx += 256) {
        int cl = idx / 64, rr = idx % 64; int o = rr / 16, l = rr % 16;
        float acc = (base + cl == 64) ? d2b[o] : 0.0f;
        for (int i = 0; i < 8; i++)
            for (int kk = 0; kk < 2; kk++) {
                int ls = l - kk;
                if (ls >= 0 && ls < 15)
                    acc += d2w[(i * 4 + o) * 2 + kk] * Bf[cl][i * 15 + ls];
            }
        A[cl][rr] = acc;
    }
    __syncthreads();
    for (int idx = tid; idx < 13 * 32; idx += 256) {
        int cl = idx / 32, rr = idx % 32; int ch = rr / 8, jj = rr % 8;
        float acc = (base + cl == 64) ? f1b[jj] : 0.0f;
        for (int l = 0; l < 16; l++)
            acc += f1w[jj * 16 + l] * A[cl][ch * 16 + l];
        Bf[cl][rr] = acc;
    }
    __syncthreads();
    for (int idx = tid; idx < 13 * 16; idx += 256) {
        int cl = idx / 16, rr = idx % 16; int ch = rr / 4, m = rr % 4;
        int col = base + cl;
        if (col > 64) continue;
        float acc = (col == 64) ? f2b[m] : 0.0f;
        for (int j = 0; j < 8; j++)
            acc += f2w[m * 8 + j] * Bf[cl][ch * 8 + j];
        if (col < 64) W[OFF_M + rr * 64 + col] = acc;
        else          W[OFF_MB + rr] = acc;
    }
}

// ---------------------------------------------------------------------------
// one layer-direction (this WAVE's dir), Din=16, E=2 elems per 8-lane slot.
// Register shape identical to the round-0 no-spill layer16; toff/off are
// wave-uniform SGPR values. h written at col off+u, read back from row
// 16*tprev+off (own-wave cols only -> same-wave LDS ordering suffices).
// LAST: keep hn in regs, rewrite sigm(hn) after the loop (head input).
// ---------------------------------------------------------------------------
template<bool LAST>
__device__ __forceinline__ void layer16d(
    const float* __restrict__ Wi, const float* __restrict__ Wh,
    const float* __restrict__ Bs,
    const float* __restrict__ h0s, const float* __restrict__ c0s,
    int gelem0, int u, int toff, int off,
    float* const (&lin)[2], float* const (&lout)[2])
{
    f32x4 wiv[4][4];   // 4 gates x 16 input weights (this dir only)
    f32x4 whv[4][2];   // 4 gates x 8 hidden weights
    f32x4 bsv;
#pragma unroll
    for (int g = 0; g < 4; g++) {
        const int r = u + 8 * g;
        const f32x4* wr = reinterpret_cast<const f32x4*>(Wi + r * 16);
        wiv[g][0] = wr[0]; wiv[g][1] = wr[1]; wiv[g][2] = wr[2]; wiv[g][3] = wr[3];
        const f32x4* ur = reinterpret_cast<const f32x4*>(Wh + r * 8);
        whv[g][0] = ur[0]; whv[g][1] = ur[1];
        bsv[g] = Bs[r];
    }
    f32x4 hg[2][2];
    float cc[2];
#pragma unroll
    for (int e = 0; e < 2; e++) {
        const f32x4* hp = reinterpret_cast<const f32x4*>(h0s + (size_t)(gelem0 + e) * 8);
        hg[e][0] = hp[0]; hg[e][1] = hp[1];
        cc[e] = c0s[(size_t)(gelem0 + e) * 8 + u];
    }
    float hreg[2][4];

#pragma unroll
    for (int s = 0; s < 4; s++) {
        const int t = s ^ toff;                 // fwd: s, bwd: 3-s (toff SGPR)
        const int tprev = (s - 1) ^ toff;       // valid for s >= 1
        f32x2 acc[2][4];
#pragma unroll
        for (int e = 0; e < 2; e++) {
            const f32x4* ip = reinterpret_cast<const f32x4*>(lin[e] + 16 * t);
            f32x4 i0 = ip[0], i1 = ip[1], i2 = ip[2], i3 = ip[3];
            f32x4 ha, hb;
            if (s == 0) { ha = hg[e][0]; hb = hg[e][1]; }
            else {
                const f32x4* hp = reinterpret_cast<const f32x4*>(lout[e] + 16 * tprev + off);
                ha = hp[0]; hb = hp[1];
            }
            f32x2 xin[8];
            xin[0] = f32x2{i0.x, i0.y}; xin[1] = f32x2{i0.z, i0.w};
            xin[2] = f32x2{i1.x, i1.y}; xin[3] = f32x2{i1.z, i1.w};
            xin[4] = f32x2{i2.x, i2.y}; xin[5] = f32x2{i2.z, i2.w};
            xin[6] = f32x2{i3.x, i3.y}; xin[7] = f32x2{i3.z, i3.w};
            f32x2 hx[4];
            hx[0] = f32x2{ha.x, ha.y}; hx[1] = f32x2{ha.z, ha.w};
            hx[2] = f32x2{hb.x, hb.y}; hx[3] = f32x2{hb.z, hb.w};
#pragma unroll
            for (int g = 0; g < 4; g++) {
                f32x2 a = f32x2{bsv[g], 0.0f};
#pragma unroll
                for (int j = 0; j < 4; j++) {
                    f32x2 wlo = f32x2{wiv[g][j].x, wiv[g][j].y};
                    f32x2 whi = f32x2{wiv[g][j].z, wiv[g][j].w};
                    a = __builtin_elementwise_fma(xin[2 * j], wlo, a);
                    a = __builtin_elementwise_fma(xin[2 * j + 1], whi, a);
                }
#pragma unroll
                for (int j = 0; j < 2; j++) {
                    f32x2 wlo = f32x2{whv[g][j].x, whv[g][j].y};
                    f32x2 whi = f32x2{whv[g][j].z, whv[g][j].w};
                    a = __builtin_elementwise_fma(hx[2 * j], wlo, a);
                    a = __builtin_elementwise_fma(hx[2 * j + 1], whi, a);
                }
                acc[e][g] = a;
            }
        }
#pragma unroll
        for (int e = 0; e < 2; e++) {
            float si = sigm(acc[e][0].x + acc[e][0].y);
            float sf = sigm(acc[e][1].x + acc[e][1].y);
            float tg = tanhx(acc[e][2].x + acc[e][2].y);
            float so = sigm(acc[e][3].x + acc[e][3].y);
            cc[e] = fmaf(sf, cc[e], si * tg);
            float hn = so * tanhx(cc[e]);
            lout[e][16 * t + off + u] = hn;    // readback next step + next-layer input
            if (LAST) hreg[e][s] = hn;
        }
    }
    if (LAST) {
#pragma unroll
        for (int e = 0; e < 2; e++)
#pragma unroll
            for (int s = 0; s < 4; s++) {
                const int t = s ^ toff;
                lout[e][16 * t + off + u] = sigm(hreg[e][s]);
            }
    }
}

// layer 0 (Din=2), input in registers, this wave's dir only
__device__ __forceinline__ void layer2d(
    const float* __restrict__ Wi, const float* __restrict__ Wh,
    const float* __restrict__ Bs,
    const float* __restrict__ h0s, const float* __restrict__ c0s,
    int gelem0, int u, int toff, int off,
    const f32x2 (&xin2)[2][4], float* const (&lout)[2])
{
    f32x2 wiv[4];
    f32x4 whv[4][2];
    f32x4 bsv;
#pragma unroll
    for (int g = 0; g < 4; g++) {
        const int r = u + 8 * g;
        wiv[g] = *reinterpret_cast<const f32x2*>(Wi + r * 2);
        const f32x4* ur = reinterpret_cast<const f32x4*>(Wh + r * 8);
        whv[g][0] = ur[0]; whv[g][1] = ur[1];
        bsv[g] = Bs[r];
    }
    f32x4 hg[2][2];
    float cc[2];
#pragma unroll
    for (int e = 0; e < 2; e++) {
        const f32x4* hp = reinterpret_cast<const f32x4*>(h0s + (size_t)(gelem0 + e) * 8);
        hg[e][0] = hp[0]; hg[e][1] = hp[1];
        cc[e] = c0s[(size_t)(gelem0 + e) * 8 + u];
    }

#pragma unroll
    for (int s = 0; s < 4; s++) {
        const int t = s ^ toff;
        const int tprev = (s - 1) ^ toff;
        f32x2 acc[2][4];
#pragma unroll
        for (int e = 0; e < 2; e++) {
            // register-array access kept compile-time on both arms (rule #20);
            // toff is wave-uniform so the select is a uniform cndmask.
            f32x2 xv = toff ? xin2[e][3 - s] : xin2[e][s];
            f32x4 ha, hb;
            if (s == 0) { ha = hg[e][0]; hb = hg[e][1]; }
            else {
                const f32x4* hp = reinterpret_cast<const f32x4*>(lout[e] + 16 * tprev + off);
                ha = hp[0]; hb = hp[1];
            }
            f32x2 hx[4];
            hx[0] = f32x2{ha.x, ha.y}; hx[1] = f32x2{ha.z, ha.w};
            hx[2] = f32x2{hb.x, hb.y}; hx[3] = f32x2{hb.z, hb.w};
#pragma unroll
            for (int g = 0; g < 4; g++) {
                f32x2 a = __builtin_elementwise_fma(xv, wiv[g], f32x2{bsv[g], 0.0f});
#pragma unroll
                for (int j = 0; j < 2; j++) {
                    f32x2 wlo = f32x2{whv[g][j].x, whv[g][j].y};
                    f32x2 whi = f32x2{whv[g][j].z, whv[g][j].w};
                    a = __builtin_elementwise_fma(hx[2 * j], wlo, a);
                    a = __builtin_elementwise_fma(hx[2 * j + 1], whi, a);
                }
                acc[e][g] = a;
            }
        }
#pragma unroll
        for (int e = 0; e < 2; e++) {
            float si = sigm(acc[e][0].x + acc[e][0].y);
            float sf = sigm(acc[e][1].x + acc[e][1].y);
            float tg = tanhx(acc[e][2].x + acc[e][2].y);
            float so = sigm(acc[e][3].x + acc[e][3].y);
            cc[e] = fmaf(sf, cc[e], si * tg);
            lout[e][16 * t + off + u] = so * tanhx(cc[e]);
        }
    }
}

// ---------------------------------------------------------------------------
// main: block = 128 threads = 2 waves over the SAME 16 elements;
// wave 0 = fwd, wave 1 = bwd (dir wave-uniform via readfirstlane).
// 8 lanes x E=2 per slot, as round 0.
// ---------------------------------------------------------------------------
__global__ __launch_bounds__(128, 3) void lstm_main(
    const float* __restrict__ x, const float* __restrict__ h0,
    const float* __restrict__ c0, const float* __restrict__ W,
    float* __restrict__ out, int B)
{
    __shared__ float yb[2][16 * 68];   // ping-pong activations, stride 68
    const int tid = threadIdx.x;
    const int lane = tid & 63;
    const int u = lane & 7;
    const int slot = lane >> 3;                  // 0..7
    const int dir = __builtin_amdgcn_readfirstlane(tid >> 6);  // SGPR 0/1
    const int toff = dir ? 3 : 0;
    const int off  = dir * 8;
    const int row0 = slot * 2;
    const int gelem0 = blockIdx.x * 16 + row0;
    const size_t B8 = (size_t)B * 8;

    float* y0[2]; float* y1[2];
#pragma unroll
    for (int e = 0; e < 2; e++) {
        y0[e] = &yb[0][(row0 + e) * 68];
        y1[e] = &yb[1][(row0 + e) * 68];
    }

    f32x2 xin2[2][4];
#pragma unroll
    for (int e = 0; e < 2; e++) {
        const f32x4* xp = reinterpret_cast<const f32x4*>(x + (size_t)(gelem0 + e) * 8);
        f32x4 a = xp[0], b = xp[1];
        xin2[e][0] = f32x2{a.x, a.y}; xin2[e][1] = f32x2{a.z, a.w};
        xin2[e][2] = f32x2{b.x, b.y}; xin2[e][3] = f32x2{b.z, b.w};
    }

    // layer 0 (this wave's dir) -> y0
    layer2d(W + OFF_WIH0 + dir * 64, W + OFF_WHH0 + dir * 256, W + OFF_B0 + dir * 32,
            h0 + (size_t)dir * B8, c0 + (size_t)dir * B8,
            gelem0, u, toff, off, xin2, y0);
    __syncthreads();

    // layers 1..4: ping-pong; layer 5 writes sigm() into y1 for the head
#pragma unroll
    for (int l = 1; l <= 4; l++) {
        float* const (&lin)[2] = (l & 1) ? y0 : y1;
        float* const (&lout)[2] = (l & 1) ? y1 : y0;
        const float* wi = W + OFF_WIH + (size_t)(l - 1) * 1024 + dir * 512;
        const float* wh = W + OFF_WHH + (size_t)(l - 1) * 512 + dir * 256;
        const float* bb = W + OFF_B + (size_t)(l - 1) * 64 + dir * 32;
        const int si = 2 * l + dir;
        layer16d<false>(wi, wh, bb,
                        h0 + (size_t)si * B8, c0 + (size_t)si * B8,
                        gelem0, u, toff, off, lin, lout);
        __syncthreads();
    }
    {
        const float* wi = W + OFF_WIH + (size_t)4 * 1024 + dir * 512;
        const float* wh = W + OFF_WHH + (size_t)4 * 512 + dir * 256;
        const float* bb = W + OFF_B + (size_t)4 * 64 + dir * 32;
        const int si = 10 + dir;
        layer16d<true>(wi, wh, bb,
                       h0 + (size_t)si * B8, c0 + (size_t)si * B8,
                       gelem0, u, toff, off, y0, y1);
        __syncthreads();
    }

    // head: y1 holds sigm(s[64]); this wave computes output rows off..off+7,
    // lane -> row o = off + u, for its slot's E=2 elements.
    {
        const int o = off + u;                   // 0..15 across the two waves
        const f32x4* Mr = reinterpret_cast<const f32x4*>(W + OFF_M + o * 64);
        const float bo = W[OFF_MB + o];
#pragma unroll
        for (int e = 0; e < 2; e++) {
            float a0 = bo;
#pragma unroll
            for (int q = 0; q < 16; q++) {
                f32x4 sv = *reinterpret_cast<const f32x4*>(y1[e] + 4 * q);
                f32x4 m0 = Mr[q];
                a0 = fmaf(sv.x, m0.x, a0); a0 = fmaf(sv.y, m0.y, a0);
                a0 = fmaf(sv.z, m0.z, a0); a0 = fmaf(sv.w, m0.w, a0);
            }
            out[(size_t)(gelem0 + e) * 16 + o] = tanhx(a0);
        }
    }
}

extern "C" void kernel_launch(void* const* d_in, const int* in_sizes, int n_in,
                              void* d_out, int out_size, void* d_ws, size_t ws_size,
                              hipStream_t stream)
{
    const float* x    = (const float*)d_in[0];
    const float* h0   = (const float*)d_in[1];
    const float* c0   = (const float*)d_in[2];
    const float* wih0 = (const float*)d_in[3];
    const float* whh0 = (const float*)d_in[4];
    const float* bih0 = (const float*)d_in[5];
    const float* bhh0 = (const float*)d_in[6];
    const float* wih  = (const float*)d_in[7];
    const float* whh  = (const float*)d_in[8];
    const float* bih  = (const float*)d_in[9];
    const float* bhh  = (const float*)d_in[10];
    const float* c1w  = (const float*)d_in[11];
    const float* c1b  = (const float*)d_in[12];
    const float* c2w  = (const float*)d_in[13];
    const float* c2b  = (const float*)d_in[14];
    const float* d1w  = (const float*)d_in[15];
    const float* d1b  = (const float*)d_in[16];
    const float* d2w  = (const float*)d_in[17];
    const float* d2b  = (const float*)d_in[18];
    const float* f1w  = (const float*)d_in[19];
    const float* f1b  = (const float*)d_in[20];
    const float* f2w  = (const float*)d_in[21];
    const float* f2b  = (const float*)d_in[22];

    float* W = (float*)d_ws;
    const int B = in_sizes[0] / 8;

    prep_all<<<41, 256, 0, stream>>>(wih0, whh0, bih0, bhh0, wih, whh, bih, bhh,
                                     c1w, c1b, c2w, c2b, d1w, d1b, d2w, d2b,
                                     f1w, f1b, f2w, f2b, W);
    lstm_main<<<B / 16, 128, 0, stream>>>(x, h0, c0, W, (float*)d_out, B);
}